// Round 1
// baseline (272.785 us; speedup 1.0000x reference)
//
#include <hip/hip_runtime.h>
#include <math.h>

// PredictSpanSet: BS=32, BT=1024, DIM=512.
// Key identity: score[b,t] = dot(sen_vecs[b,t,:], y_w[b,:]) + c_w[b]
//   where y_w[b,d] = sum_e W_w[e,d] * x[b,e],  c_w[b] = dot(bias_w, x[b]).
// This removes the (bt,d)x(e,d) GEMMs entirely; the kernel is memory-bound on
// reading sen_vecs (64 MB) and writing the (32,1024,1024) f32 output (128 MB).

#define BS 32
#define BT 1024
#define DIM 512
#define NEG_MASK -1000000.0f
#define NEG_SPAN -1000.0f

// ---------------------------------------------------------------------------
// K1: Y[w][b][d] = sum_e W_w[e][d]*x[b][e]   (grid.x 0..7: 64 d's per block)
//     C[w][b]    = sum_e bias_w[e]*x[b][e]   (grid.x == 8)
// grid = (9, 3), block = 256
// ---------------------------------------------------------------------------
__global__ __launch_bounds__(256) void k1_proj(
    const float* __restrict__ x,
    const float* __restrict__ Wb, const float* __restrict__ bb,
    const float* __restrict__ Wi, const float* __restrict__ bi,
    const float* __restrict__ Wo, const float* __restrict__ bo,
    float* __restrict__ Y, float* __restrict__ C)
{
    const int w = blockIdx.y;
    const float* __restrict__ W    = (w == 0) ? Wb : (w == 1) ? Wi : Wo;
    const float* __restrict__ bias = (w == 0) ? bb : (w == 1) ? bi : bo;
    const int tid = threadIdx.x;

    if (blockIdx.x == 8) {
        // c_w[b] = dot(bias_w, x[b]) — wave v handles batches v, v+4, ...
        const int v = tid >> 6, l = tid & 63;
        for (int b = v; b < BS; b += 4) {
            float acc = 0.f;
            for (int e = l; e < DIM; e += 64) acc += bias[e] * x[b * DIM + e];
            #pragma unroll
            for (int o = 32; o >= 1; o >>= 1) acc += __shfl_xor(acc, o);
            if (l == 0) C[w * BS + b] = acc;
        }
        return;
    }

    __shared__ float xs[BS * DIM];          // 64 KB: whole X in LDS
    for (int k = tid; k < BS * DIM; k += 256) xs[k] = x[k];
    __syncthreads();

    const int d0 = blockIdx.x * 64;
    const int dt = tid & 63, bg = tid >> 6;  // 64 d-lanes x 4 batch-groups
    const int d  = d0 + dt;

    float acc[8];
    #pragma unroll
    for (int i = 0; i < 8; i++) acc[i] = 0.f;
    for (int e = 0; e < DIM; e++) {
        const float wv = W[e * DIM + d];     // coalesced across dt
        #pragma unroll
        for (int i = 0; i < 8; i++)
            acc[i] += wv * xs[(bg * 8 + i) * DIM + e];  // LDS broadcast
    }
    #pragma unroll
    for (int i = 0; i < 8; i++)
        Y[w * BS * DIM + (bg * 8 + i) * DIM + d] = acc[i];
}

// ---------------------------------------------------------------------------
// K2a: per-row scores + lse. One wave per row t; 4 rows per 256-thread block.
// grid = 8192 (= 32 batches * 256 blocks), block = 256
// ---------------------------------------------------------------------------
__global__ __launch_bounds__(256) void k2a_scores(
    const float* __restrict__ sv, const int* __restrict__ mask,
    const float* __restrict__ Y, const float* __restrict__ C,
    float* __restrict__ SB, float* __restrict__ SI, float* __restrict__ SO,
    float* __restrict__ LSE)
{
    __shared__ float ys[3 * DIM];            // y_b | y_i | y_o for this batch
    const int blk = blockIdx.x;
    const int b   = blk >> 8;                // 256 blocks per batch
    const int t0  = (blk & 255) * 4;
    const int tid = threadIdx.x;

    for (int k = tid; k < 3 * DIM; k += 256) {
        const int w = k >> 9, d = k & (DIM - 1);
        ys[k] = Y[w * BS * DIM + b * DIM + d];
    }
    __syncthreads();

    const int v = tid >> 6, l = tid & 63;
    const int t = t0 + v;

    const float4* __restrict__ yb4 = (const float4*)(ys);
    const float4* __restrict__ yi4 = (const float4*)(ys + DIM);
    const float4* __restrict__ yo4 = (const float4*)(ys + 2 * DIM);
    const float4* __restrict__ svp =
        (const float4*)(sv + (size_t)(b * BT + t) * DIM);

    const float4 s1 = svp[l];        // d = 4*l       (coalesced 1 KB segment)
    const float4 s2 = svp[64 + l];   // d = 256 + 4*l (coalesced 1 KB segment)

    float4 y1, y2;
    y1 = yb4[l]; y2 = yb4[64 + l];
    float aB = s1.x*y1.x + s1.y*y1.y + s1.z*y1.z + s1.w*y1.w
             + s2.x*y2.x + s2.y*y2.y + s2.z*y2.z + s2.w*y2.w;
    y1 = yi4[l]; y2 = yi4[64 + l];
    float aI = s1.x*y1.x + s1.y*y1.y + s1.z*y1.z + s1.w*y1.w
             + s2.x*y2.x + s2.y*y2.y + s2.z*y2.z + s2.w*y2.w;
    y1 = yo4[l]; y2 = yo4[64 + l];
    float aO = s1.x*y1.x + s1.y*y1.y + s1.z*y1.z + s1.w*y1.w
             + s2.x*y2.x + s2.y*y2.y + s2.z*y2.z + s2.w*y2.w;

    #pragma unroll
    for (int o = 32; o >= 1; o >>= 1) {
        aB += __shfl_xor(aB, o);
        aI += __shfl_xor(aI, o);
        aO += __shfl_xor(aO, o);
    }

    if (l == 0) {
        float sb = aB + C[0 * BS + b];
        float si = aI + C[1 * BS + b];
        float so = aO + C[2 * BS + b];
        if (mask[b * BT + t] == 0) { sb = NEG_MASK; si = NEG_MASK; so = 0.f; }
        const float m   = fmaxf(sb, fmaxf(si, so));
        const float lse = m + logf(expf(sb - m) + expf(si - m) + expf(so - m));
        const int idx = b * BT + t;
        SB[idx] = sb; SI[idx] = si; SO[idx] = so; LSE[idx] = lse;
    }
}

// ---------------------------------------------------------------------------
// K2b: per-batch block scan of lse and si; emit A[b,t], B[b,t].
// grid = 32, block = 1024
// ---------------------------------------------------------------------------
__global__ __launch_bounds__(1024) void k2b_scan(
    const float* __restrict__ SB, const float* __restrict__ SI,
    const float* __restrict__ SO, const float* __restrict__ LSE,
    float* __restrict__ A, float* __restrict__ Bv)
{
    __shared__ float sL[BT], sS[BT];
    const int b = blockIdx.x, t = threadIdx.x;
    const float l0 = LSE[b * BT + t];
    const float s0 = SI[b * BT + t];
    sL[t] = l0; sS[t] = s0;
    __syncthreads();

    for (int off = 1; off < BT; off <<= 1) {    // Hillis–Steele inclusive scan
        float a = 0.f, c = 0.f;
        if (t >= off) { a = sL[t - off]; c = sS[t - off]; }
        __syncthreads();
        if (t >= off) { sL[t] += a; sS[t] += c; }
        __syncthreads();
    }

    const float total = sL[BT - 1];             // full = sum of all lse
    const float pl = sL[t] - l0;                // exclusive prefix of lse
    const float ps = sS[t] - s0;                // exclusive prefix of si
    A [b * BT + t] = SB[b * BT + t] + pl - ps - total;
    Bv[b * BT + t] = ps + (total - sL[t]) + SO[b * BT + t];  // total-pl-l0 = suffix(t+1)
}

// ---------------------------------------------------------------------------
// K3: out[b,i,j] = (j>=i) ? A[b,i]+B[b,j] : NEG_SPAN — float4 streaming store.
// grid = 32768, block = 256  (one float4 per thread; 256 threads = one i-row)
// ---------------------------------------------------------------------------
__global__ __launch_bounds__(256) void k3_span(
    const float* __restrict__ A, const float* __restrict__ Bv,
    float4* __restrict__ out)
{
    const int idx = blockIdx.x * 256 + threadIdx.x;  // 8,388,608 float4 slots
    const int b  = idx >> 18;
    const int r  = idx & 0x3FFFF;
    const int i  = r >> 8;
    const int j4 = r & 255;

    const float a = A[b * BT + i];                    // wave-uniform (s-load)
    const float4 bb4 = ((const float4*)(Bv + b * BT))[j4];
    const int j = j4 * 4;
    float4 o;
    o.x = (j     >= i) ? a + bb4.x : NEG_SPAN;
    o.y = (j + 1 >= i) ? a + bb4.y : NEG_SPAN;
    o.z = (j + 2 >= i) ? a + bb4.z : NEG_SPAN;
    o.w = (j + 3 >= i) ? a + bb4.w : NEG_SPAN;
    out[idx] = o;
}

// ---------------------------------------------------------------------------
extern "C" void kernel_launch(void* const* d_in, const int* in_sizes, int n_in,
                              void* d_out, int out_size, void* d_ws, size_t ws_size,
                              hipStream_t stream) {
    const float* x   = (const float*)d_in[0];
    const float* sv  = (const float*)d_in[1];
    const int*   msk = (const int*)  d_in[2];
    const float* Wb  = (const float*)d_in[3];
    const float* bb  = (const float*)d_in[4];
    const float* Wi  = (const float*)d_in[5];
    const float* bi  = (const float*)d_in[6];
    const float* Wo  = (const float*)d_in[7];
    const float* bo  = (const float*)d_in[8];

    float* ws = (float*)d_ws;
    // workspace layout (floats): total 246,272 floats ≈ 0.94 MB
    float* Y   = ws;                  // 3*32*512 = 49152
    float* C   = ws + 49152;          // 96 (padded to 512)
    float* SB  = ws + 49664;          // 32*1024
    float* SI  = SB + BS * BT;
    float* SO  = SI + BS * BT;
    float* LSE = SO + BS * BT;
    float* A   = LSE + BS * BT;
    float* Bv  = A + BS * BT;

    k1_proj  <<<dim3(9, 3), 256, 0, stream>>>(x, Wb, bb, Wi, bi, Wo, bo, Y, C);
    k2a_scores<<<BS * 256, 256, 0, stream>>>(sv, msk, Y, C, SB, SI, SO, LSE);
    k2b_scan <<<BS, 1024, 0, stream>>>(SB, SI, SO, LSE, A, Bv);
    k3_span  <<<32768, 256, 0, stream>>>(A, Bv, (float4*)d_out);
}